// Round 4
// baseline (1453.220 us; speedup 1.0000x reference)
//
#include <hip/hip_runtime.h>

// NNUE forward on MI355X.
// Pipeline: init(convert W to f16, fill perm=-1, zero hdr) -> histogram ->
// padded prefix -> scatter (counting sort by bucket over 2B rows) ->
// grouped GEMM (fp16 MFMA 16x16x32, gathered rows, relu, scatter to c[B,512])
// -> MLP (layer1 MFMA fp16, layers 2/3 fp32 VALU), out = mlp(c)*stm.

#define NB 65536          // batch
#define NIN 640
#define NH 256
#define NE 8
#define PB 128            // rows per GEMM slot-block (padding quantum)
#define NPERM (2*NB + NE*PB)   // 132096
#define N_WFT (NE*NH*NIN)      // 1310720
#define N_W1  (32*512)

typedef _Float16 f16_t;
typedef f16_t f16x8 __attribute__((ext_vector_type(8)));
typedef float f32x4 __attribute__((ext_vector_type(4)));

// ---------------- init: convert weights to f16, fill perm, zero header ----
__global__ void k_init(const float* __restrict__ Wft, const float* __restrict__ W1,
                       f16_t* __restrict__ Whf, f16_t* __restrict__ W1h,
                       int* __restrict__ hdr, int* __restrict__ perm)
{
    int idx = blockIdx.x * 256 + threadIdx.x;
    int stride = gridDim.x * 256;
    for (int i = idx; i < N_WFT / 8; i += stride) {
        const float4* src = (const float4*)Wft + (size_t)i * 2;
        float4 v0 = src[0], v1 = src[1];
        f16x8 h;
        h[0]=(f16_t)v0.x; h[1]=(f16_t)v0.y; h[2]=(f16_t)v0.z; h[3]=(f16_t)v0.w;
        h[4]=(f16_t)v1.x; h[5]=(f16_t)v1.y; h[6]=(f16_t)v1.z; h[7]=(f16_t)v1.w;
        *((f16x8*)Whf + i) = h;
    }
    for (int i = idx; i < N_W1 / 8; i += stride) {
        const float4* src = (const float4*)W1 + (size_t)i * 2;
        float4 v0 = src[0], v1 = src[1];
        f16x8 h;
        h[0]=(f16_t)v0.x; h[1]=(f16_t)v0.y; h[2]=(f16_t)v0.z; h[3]=(f16_t)v0.w;
        h[4]=(f16_t)v1.x; h[5]=(f16_t)v1.y; h[6]=(f16_t)v1.z; h[7]=(f16_t)v1.w;
        *((f16x8*)W1h + i) = h;
    }
    for (int i = idx; i < NPERM; i += stride) perm[i] = -1;
    if (idx < 64) hdr[idx] = 0;
}

// ---------------- histogram over 2B rows ---------------------------------
__global__ void k_hist(const int* __restrict__ wb, const int* __restrict__ bb,
                       int* __restrict__ hdr)
{
    int i = blockIdx.x * 256 + threadIdx.x;          // 0 .. 2*NB-1
    int b = (i < NB ? wb[i] : bb[i - NB]) & 7;
    atomicAdd(&hdr[b], 1);
}

// ---------------- padded prefix sum (tiny) -------------------------------
__global__ void k_prefix(int* __restrict__ hdr)
{
    if (threadIdx.x == 0 && blockIdx.x == 0) {
        int* cnt  = hdr;
        int* pofs = hdr + 8;    // pofs[0..8]
        int* cur  = hdr + 17;   // cur[0..7]
        int acc = 0;
        for (int e = 0; e < 8; ++e) {
            pofs[e] = acc; cur[e] = acc;
            acc += ((cnt[e] + PB - 1) / PB) * PB;
        }
        pofs[8] = acc;
    }
}

// ---------------- scatter rows into bucket-sorted slots ------------------
__global__ void k_scatter(const int* __restrict__ wb, const int* __restrict__ bb,
                          int* __restrict__ hdr, int* __restrict__ perm)
{
    int i = blockIdx.x * 256 + threadIdx.x;
    int b = (i < NB ? wb[i] : bb[i - NB]) & 7;
    int pos = atomicAdd(&hdr[17 + b], 1);
    perm[pos] = i;
}

// ---------------- grouped gathered GEMM + relu ---------------------------
// grid = 2 * (NPERM/PB) blocks; blk&1 selects output-col half (128 of 256).
// Tile: 128 rows x 128 cols x K=640 (BK=64), 4 waves (2x2), 4x4 frags/wave.
__global__ __launch_bounds__(256, 2)
void k_gemm(const float* __restrict__ wf, const float* __restrict__ bfeat,
            const f16_t* __restrict__ Whf, const int* __restrict__ hdr,
            const int* __restrict__ perm, f16_t* __restrict__ cbuf)
{
    __shared__ f16_t As[128 * 64];
    __shared__ f16_t Bs[128 * 64];
    __shared__ int rowids[128];

    const int tid = threadIdx.x;
    const int blk = blockIdx.x;
    const int bn  = blk & 1;
    const int sb  = blk >> 1;
    const int slot0 = sb * PB;

    const int* pofs = hdr + 8;
    const int total = pofs[8];
    if (slot0 >= total) return;
    int e = 0;
    #pragma unroll
    for (int i = 1; i < 8; ++i) if (slot0 >= pofs[i]) e = i;

    if (tid < 128) rowids[tid] = perm[slot0 + tid];
    __syncthreads();

    const f16_t* We = Whf + (size_t)e * (NH * NIN) + (size_t)bn * 128 * NIN;

    f32x4 acc[4][4];
    #pragma unroll
    for (int m = 0; m < 4; ++m)
        #pragma unroll
        for (int n = 0; n < 4; ++n) acc[m][n] = (f32x4){0.f, 0.f, 0.f, 0.f};

    const int wid = tid >> 6;
    const int lane = tid & 63;
    const int wr = wid >> 1, wc = wid & 1;
    const int l15 = lane & 15, l4 = lane >> 4;

    for (int ks = 0; ks < NIN / 64; ++ks) {
        const int k0 = ks * 64;
        __syncthreads();
        // stage A: 128 rows x 64 k, fp32 gather -> f16, swizzled LDS
        {
            const int kg = tid & 7;          // 8 lanes x 8 floats = 64 k
            const int rbase = tid >> 3;      // 32 rows per pass
            #pragma unroll
            for (int p = 0; p < 4; ++p) {
                int row = rbase + p * 32;
                int r = rowids[row];
                float4 v0 = {0.f,0.f,0.f,0.f}, v1 = {0.f,0.f,0.f,0.f};
                if (r >= 0) {
                    const float* src = (r < NB ? wf + (size_t)r * NIN
                                               : bfeat + (size_t)(r - NB) * NIN) + k0 + kg * 8;
                    v0 = *(const float4*)(src);
                    v1 = *(const float4*)(src + 4);
                }
                f16x8 h;
                h[0]=(f16_t)v0.x; h[1]=(f16_t)v0.y; h[2]=(f16_t)v0.z; h[3]=(f16_t)v0.w;
                h[4]=(f16_t)v1.x; h[5]=(f16_t)v1.y; h[6]=(f16_t)v1.z; h[7]=(f16_t)v1.w;
                int byte = (row * 64 + kg * 8) * 2;
                *(f16x8*)((char*)As + (byte ^ ((row & 7) << 4))) = h;
            }
        }
        // stage B: 128 n x 64 k from Whf[e] (row-major [n][640])
        {
            const int kg = tid & 7;
            const int nbase = tid >> 3;
            #pragma unroll
            for (int p = 0; p < 4; ++p) {
                int n = nbase + p * 32;
                f16x8 h = *(const f16x8*)(We + (size_t)n * NIN + k0 + kg * 8);
                int byte = (n * 64 + kg * 8) * 2;
                *(f16x8*)((char*)Bs + (byte ^ ((n & 7) << 4))) = h;
            }
        }
        __syncthreads();
        // compute
        #pragma unroll
        for (int kk = 0; kk < 2; ++kk) {
            f16x8 af[4], bfr[4];
            const int kidx = kk * 32 + l4 * 8;
            #pragma unroll
            for (int m = 0; m < 4; ++m) {
                int row = wr * 64 + m * 16 + l15;
                int byte = (row * 64 + kidx) * 2;
                af[m] = *(const f16x8*)((const char*)As + (byte ^ ((row & 7) << 4)));
            }
            #pragma unroll
            for (int n = 0; n < 4; ++n) {
                int col = wc * 64 + n * 16 + l15;
                int byte = (col * 64 + kidx) * 2;
                bfr[n] = *(const f16x8*)((const char*)Bs + (byte ^ ((col & 7) << 4)));
            }
            #pragma unroll
            for (int m = 0; m < 4; ++m)
                #pragma unroll
                for (int n = 0; n < 4; ++n)
                    acc[m][n] = __builtin_amdgcn_mfma_f32_16x16x32_f16(af[m], bfr[n], acc[m][n], 0, 0, 0);
        }
    }

    // epilogue: relu -> f16 -> scatter into c[B,512]
    #pragma unroll
    for (int m = 0; m < 4; ++m) {
        #pragma unroll
        for (int j = 0; j < 4; ++j) {
            int row = wr * 64 + m * 16 + l4 * 4 + j;
            int r = rowids[row];
            if (r < 0) continue;
            size_t drow; int coff;
            if (r < NB) { drow = r; coff = 0; } else { drow = r - NB; coff = 256; }
            f16_t* dst = cbuf + drow * 512 + coff + bn * 128 + wc * 64 + l15;
            #pragma unroll
            for (int n = 0; n < 4; ++n) {
                float v = acc[m][n][j];
                v = v > 0.f ? v : 0.f;
                dst[n * 16] = (f16_t)v;
            }
        }
    }
}

// ---------------- MLP: 512->32 (MFMA) -> 32->32 -> 32->1, * stm ----------
__global__ __launch_bounds__(256, 2)
void k_mlp(const f16_t* __restrict__ cbuf, const f16_t* __restrict__ W1h,
           const float* __restrict__ b1, const float* __restrict__ W2,
           const float* __restrict__ b2, const float* __restrict__ W3,
           const float* __restrict__ b3, const float* __restrict__ stm,
           float* __restrict__ out)
{
    __shared__ f16_t cs[64 * 512];
    __shared__ float h1s[64][33];

    const int tid = threadIdx.x;
    const int s0 = blockIdx.x * 64;

    #pragma unroll
    for (int it = 0; it < 16; ++it) {
        int idx = it * 256 + tid;
        int row = idx >> 6;
        int tr = idx & 63;
        f16x8 v = *(const f16x8*)(cbuf + (size_t)(s0 + row) * 512 + tr * 8);
        int byte = (row * 512 + tr * 8) * 2;
        *(f16x8*)((char*)cs + (byte ^ ((row & 7) << 4))) = v;
    }
    __syncthreads();

    const int wid = tid >> 6, lane = tid & 63;
    const int l15 = lane & 15, l4 = lane >> 4;
    f32x4 acc0 = (f32x4){0.f,0.f,0.f,0.f};
    f32x4 acc1 = (f32x4){0.f,0.f,0.f,0.f};
    #pragma unroll 4
    for (int ks = 0; ks < 16; ++ks) {
        int k = ks * 32 + l4 * 8;
        int row = wid * 16 + l15;
        int byte = (row * 512 + k) * 2;
        f16x8 a  = *(const f16x8*)((const char*)cs + (byte ^ ((row & 7) << 4)));
        f16x8 b0 = *(const f16x8*)(W1h + (size_t)l15 * 512 + k);
        f16x8 b1v = *(const f16x8*)(W1h + (size_t)(16 + l15) * 512 + k);
        acc0 = __builtin_amdgcn_mfma_f32_16x16x32_f16(a, b0, acc0, 0, 0, 0);
        acc1 = __builtin_amdgcn_mfma_f32_16x16x32_f16(a, b1v, acc1, 0, 0, 0);
    }
    #pragma unroll
    for (int j = 0; j < 4; ++j) {
        int srow = wid * 16 + l4 * 4 + j;
        float v0 = acc0[j] + b1[l15];
        float v1 = acc1[j] + b1[16 + l15];
        h1s[srow][l15]      = v0 > 0.f ? v0 : 0.f;
        h1s[srow][16 + l15] = v1 > 0.f ? v1 : 0.f;
    }
    __syncthreads();

    // layers 2+3: 4 lanes per sample, fp32
    const int s_in = lane >> 2, q = lane & 3;
    const int srow = wid * 16 + s_in;
    float h2[8];
    #pragma unroll
    for (int n = 0; n < 8; ++n) {
        int nn = q * 8 + n;
        float sum = b2[nn];
        #pragma unroll
        for (int k = 0; k < 32; ++k) sum += W2[nn * 32 + k] * h1s[srow][k];
        h2[n] = sum > 0.f ? sum : 0.f;
    }
    float p = 0.f;
    #pragma unroll
    for (int n = 0; n < 8; ++n) p += W3[q * 8 + n] * h2[n];
    p += __shfl_xor(p, 1);
    p += __shfl_xor(p, 2);
    if (q == 0) {
        out[s0 + srow] = (p + b3[0]) * stm[s0 + srow];
    }
}

extern "C" void kernel_launch(void* const* d_in, const int* in_sizes, int n_in,
                              void* d_out, int out_size, void* d_ws, size_t ws_size,
                              hipStream_t stream)
{
    const float* wf    = (const float*)d_in[0];
    const float* bfeat = (const float*)d_in[1];
    const int*   wb    = (const int*)d_in[2];
    const int*   bb    = (const int*)d_in[3];
    const float* stm   = (const float*)d_in[4];
    const float* Wft   = (const float*)d_in[5];
    const float* W1    = (const float*)d_in[6];
    const float* b1    = (const float*)d_in[7];
    const float* W2    = (const float*)d_in[8];
    const float* b2    = (const float*)d_in[9];
    const float* W3    = (const float*)d_in[10];
    const float* b3    = (const float*)d_in[11];
    float* out = (float*)d_out;

    char* ws = (char*)d_ws;
    int*   hdr  = (int*)ws;                    // 256 B header (cnt/pofs/cur)
    int*   perm = (int*)(ws + 256);            // 132096 ints -> ends 528640
    f16_t* Whf  = (f16_t*)(ws + 528640);       // 2621440 B  -> ends 3150080
    f16_t* W1h  = (f16_t*)(ws + 3150080);      // 32768 B    -> ends 3182848
    f16_t* cbuf = (f16_t*)(ws + 3182848);      // 67108864 B -> ends ~70.3 MB

    k_init   <<<512, 256, 0, stream>>>(Wft, W1, Whf, W1h, hdr, perm);
    k_hist   <<<512, 256, 0, stream>>>(wb, bb, hdr);
    k_prefix <<<1,   64,  0, stream>>>(hdr);
    k_scatter<<<512, 256, 0, stream>>>(wb, bb, hdr, perm);
    k_gemm   <<<2 * (NPERM / PB), 256, 0, stream>>>(wf, bfeat, Whf, hdr, perm, cbuf);
    k_mlp    <<<NB / 64, 256, 0, stream>>>(cbuf, W1h, b1, W2, b2, W3, b3, stm, out);
}

// Round 5
// 472.795 us; speedup vs baseline: 3.0737x; 3.0737x over previous
//
#include <hip/hip_runtime.h>

// NNUE forward on MI355X.
// init(convert W to f16, fill perm=-1, zero hdr) -> hist (LDS-aggregated) ->
// padded prefix -> scatter (LDS-rank counting sort) ->
// grouped GEMM (fp16 MFMA 16x16x32, one 512-thr block per 128-row slot,
// full 256 cols, relu, scatter to c[B,512]) -> MLP, out = mlp(c)*stm.

#define NB 65536          // batch
#define NIN 640
#define NH 256
#define NE 8
#define PB 128            // rows per GEMM slot-block (padding quantum)
#define NPERM (2*NB + NE*PB)   // 132096
#define N_WFT (NE*NH*NIN)      // 1310720
#define N_W1  (32*512)

typedef _Float16 f16_t;
typedef f16_t f16x8 __attribute__((ext_vector_type(8)));
typedef float f32x4 __attribute__((ext_vector_type(4)));

// ---------------- init: convert weights to f16, fill perm, zero header ----
__global__ void k_init(const float* __restrict__ Wft, const float* __restrict__ W1,
                       f16_t* __restrict__ Whf, f16_t* __restrict__ W1h,
                       int* __restrict__ hdr, int* __restrict__ perm)
{
    int idx = blockIdx.x * 256 + threadIdx.x;
    int stride = gridDim.x * 256;
    for (int i = idx; i < N_WFT / 8; i += stride) {
        const float4* src = (const float4*)Wft + (size_t)i * 2;
        float4 v0 = src[0], v1 = src[1];
        f16x8 h;
        h[0]=(f16_t)v0.x; h[1]=(f16_t)v0.y; h[2]=(f16_t)v0.z; h[3]=(f16_t)v0.w;
        h[4]=(f16_t)v1.x; h[5]=(f16_t)v1.y; h[6]=(f16_t)v1.z; h[7]=(f16_t)v1.w;
        *((f16x8*)Whf + i) = h;
    }
    for (int i = idx; i < N_W1 / 8; i += stride) {
        const float4* src = (const float4*)W1 + (size_t)i * 2;
        float4 v0 = src[0], v1 = src[1];
        f16x8 h;
        h[0]=(f16_t)v0.x; h[1]=(f16_t)v0.y; h[2]=(f16_t)v0.z; h[3]=(f16_t)v0.w;
        h[4]=(f16_t)v1.x; h[5]=(f16_t)v1.y; h[6]=(f16_t)v1.z; h[7]=(f16_t)v1.w;
        *((f16x8*)W1h + i) = h;
    }
    for (int i = idx; i < NPERM; i += stride) perm[i] = -1;
    if (idx < 64) hdr[idx] = 0;
}

// ---------------- histogram: LDS-aggregated, 8 global atomics/block ------
__global__ void k_hist(const int* __restrict__ wb, const int* __restrict__ bb,
                       int* __restrict__ hdr)
{
    __shared__ int lcnt[8];
    const int tid = threadIdx.x;
    if (tid < 8) lcnt[tid] = 0;
    __syncthreads();
    int i = blockIdx.x * 256 + tid;
    int b = (i < NB ? wb[i] : bb[i - NB]) & 7;
    atomicAdd(&lcnt[b], 1);
    __syncthreads();
    if (tid < 8 && lcnt[tid] > 0) atomicAdd(&hdr[tid], lcnt[tid]);
}

// ---------------- padded prefix sum (tiny) -------------------------------
__global__ void k_prefix(int* __restrict__ hdr)
{
    if (threadIdx.x == 0 && blockIdx.x == 0) {
        int* cnt  = hdr;
        int* pofs = hdr + 8;    // pofs[0..8]
        int* cur  = hdr + 17;   // cur[0..7]
        int acc = 0;
        for (int e = 0; e < 8; ++e) {
            pofs[e] = acc; cur[e] = acc;
            acc += ((cnt[e] + PB - 1) / PB) * PB;
        }
        pofs[8] = acc;
    }
}

// ---------------- scatter: LDS rank + 8 global atomics/block -------------
__global__ void k_scatter(const int* __restrict__ wb, const int* __restrict__ bb,
                          int* __restrict__ hdr, int* __restrict__ perm)
{
    __shared__ int lcnt[8];
    __shared__ int lbase[8];
    const int tid = threadIdx.x;
    if (tid < 8) lcnt[tid] = 0;
    __syncthreads();
    int i = blockIdx.x * 256 + tid;
    int b = (i < NB ? wb[i] : bb[i - NB]) & 7;
    int rank = atomicAdd(&lcnt[b], 1);           // LDS atomic: intra-block rank
    __syncthreads();
    if (tid < 8) lbase[tid] = lcnt[tid] ? atomicAdd(&hdr[17 + tid], lcnt[tid]) : 0;
    __syncthreads();
    perm[lbase[b] + rank] = i;
}

// ---------------- grouped gathered GEMM + relu ---------------------------
// grid = NPERM/PB blocks; 512 threads (8 waves, 2x4), tile 128 rows x 256
// cols x K=640 (BK=64). Per wave 64x64 out = 4x4 frags. A gathered ONCE.
__global__ __launch_bounds__(512, 2)
void k_gemm(const float* __restrict__ wf, const float* __restrict__ bfeat,
            const f16_t* __restrict__ Whf, const int* __restrict__ hdr,
            const int* __restrict__ perm, f16_t* __restrict__ cbuf)
{
    __shared__ f16_t As[128 * 64];   // 16 KB, XOR-swizzled
    __shared__ f16_t Bs[256 * 64];   // 32 KB, XOR-swizzled
    __shared__ int rowids[128];

    const int tid = threadIdx.x;
    const int slot0 = blockIdx.x * PB;

    const int* pofs = hdr + 8;
    const int total = pofs[8];
    if (slot0 >= total) return;
    int e = 0;
    #pragma unroll
    for (int i = 1; i < 8; ++i) if (slot0 >= pofs[i]) e = i;

    if (tid < 128) rowids[tid] = perm[slot0 + tid];
    __syncthreads();

    const f16_t* We = Whf + (size_t)e * (NH * NIN);

    f32x4 acc[4][4];
    #pragma unroll
    for (int m = 0; m < 4; ++m)
        #pragma unroll
        for (int n = 0; n < 4; ++n) acc[m][n] = (f32x4){0.f, 0.f, 0.f, 0.f};

    const int wid = tid >> 6;
    const int lane = tid & 63;
    const int wr = wid >> 2, wc = wid & 3;       // 2x4 wave grid
    const int l15 = lane & 15, l4 = lane >> 4;

    for (int ks = 0; ks < NIN / 64; ++ks) {
        const int k0 = ks * 64;
        __syncthreads();
        // stage A: 128 rows x 64 k, fp32 gather -> f16, swizzled LDS
        {
            const int kg = tid & 7;          // 8 lanes x 8 floats = 64 k
            const int rbase = tid >> 3;      // 64 rows per pass
            #pragma unroll
            for (int p = 0; p < 2; ++p) {
                int row = rbase + p * 64;
                int r = rowids[row];
                float4 v0 = {0.f,0.f,0.f,0.f}, v1 = {0.f,0.f,0.f,0.f};
                if (r >= 0) {
                    const float* src = (r < NB ? wf + (size_t)r * NIN
                                               : bfeat + (size_t)(r - NB) * NIN) + k0 + kg * 8;
                    v0 = *(const float4*)(src);
                    v1 = *(const float4*)(src + 4);
                }
                f16x8 h;
                h[0]=(f16_t)v0.x; h[1]=(f16_t)v0.y; h[2]=(f16_t)v0.z; h[3]=(f16_t)v0.w;
                h[4]=(f16_t)v1.x; h[5]=(f16_t)v1.y; h[6]=(f16_t)v1.z; h[7]=(f16_t)v1.w;
                int byte = (row * 64 + kg * 8) * 2;
                *(f16x8*)((char*)As + (byte ^ ((row & 7) << 4))) = h;
            }
        }
        // stage B: 256 n x 64 k from Whf[e] (row-major [n][640])
        {
            const int kg = tid & 7;
            const int nbase = tid >> 3;
            #pragma unroll
            for (int p = 0; p < 4; ++p) {
                int n = nbase + p * 64;
                f16x8 h = *(const f16x8*)(We + (size_t)n * NIN + k0 + kg * 8);
                int byte = (n * 64 + kg * 8) * 2;
                *(f16x8*)((char*)Bs + (byte ^ ((n & 7) << 4))) = h;
            }
        }
        __syncthreads();
        // compute
        #pragma unroll
        for (int kk = 0; kk < 2; ++kk) {
            f16x8 af[4], bfr[4];
            const int kidx = kk * 32 + l4 * 8;
            #pragma unroll
            for (int m = 0; m < 4; ++m) {
                int row = wr * 64 + m * 16 + l15;
                int byte = (row * 64 + kidx) * 2;
                af[m] = *(const f16x8*)((const char*)As + (byte ^ ((row & 7) << 4)));
            }
            #pragma unroll
            for (int n = 0; n < 4; ++n) {
                int col = wc * 64 + n * 16 + l15;
                int byte = (col * 64 + kidx) * 2;
                bfr[n] = *(const f16x8*)((const char*)Bs + (byte ^ ((col & 7) << 4)));
            }
            #pragma unroll
            for (int m = 0; m < 4; ++m)
                #pragma unroll
                for (int n = 0; n < 4; ++n)
                    acc[m][n] = __builtin_amdgcn_mfma_f32_16x16x32_f16(af[m], bfr[n], acc[m][n], 0, 0, 0);
        }
    }

    // epilogue: relu -> f16 -> scatter into c[B,512]
    #pragma unroll
    for (int m = 0; m < 4; ++m) {
        #pragma unroll
        for (int j = 0; j < 4; ++j) {
            int row = wr * 64 + m * 16 + l4 * 4 + j;
            int r = rowids[row];
            if (r < 0) continue;
            size_t drow; int coff;
            if (r < NB) { drow = r; coff = 0; } else { drow = r - NB; coff = 256; }
            f16_t* dst = cbuf + drow * 512 + coff + wc * 64 + l15;
            #pragma unroll
            for (int n = 0; n < 4; ++n) {
                float v = acc[m][n][j];
                v = v > 0.f ? v : 0.f;
                dst[n * 16] = (f16_t)v;
            }
        }
    }
}

// ---------------- MLP: 512->32 (MFMA) -> 32->32 -> 32->1, * stm ----------
__global__ __launch_bounds__(256, 2)
void k_mlp(const f16_t* __restrict__ cbuf, const f16_t* __restrict__ W1h,
           const float* __restrict__ b1, const float* __restrict__ W2,
           const float* __restrict__ b2, const float* __restrict__ W3,
           const float* __restrict__ b3, const float* __restrict__ stm,
           float* __restrict__ out)
{
    __shared__ f16_t cs[64 * 512];
    __shared__ float h1s[64][33];

    const int tid = threadIdx.x;
    const int s0 = blockIdx.x * 64;

    #pragma unroll
    for (int it = 0; it < 16; ++it) {
        int idx = it * 256 + tid;
        int row = idx >> 6;
        int tr = idx & 63;
        f16x8 v = *(const f16x8*)(cbuf + (size_t)(s0 + row) * 512 + tr * 8);
        int byte = (row * 512 + tr * 8) * 2;
        *(f16x8*)((char*)cs + (byte ^ ((row & 7) << 4))) = v;
    }
    __syncthreads();

    const int wid = tid >> 6, lane = tid & 63;
    const int l15 = lane & 15, l4 = lane >> 4;
    f32x4 acc0 = (f32x4){0.f,0.f,0.f,0.f};
    f32x4 acc1 = (f32x4){0.f,0.f,0.f,0.f};
    #pragma unroll 4
    for (int ks = 0; ks < 16; ++ks) {
        int k = ks * 32 + l4 * 8;
        int row = wid * 16 + l15;
        int byte = (row * 512 + k) * 2;
        f16x8 a  = *(const f16x8*)((const char*)cs + (byte ^ ((row & 7) << 4)));
        f16x8 b0 = *(const f16x8*)(W1h + (size_t)l15 * 512 + k);
        f16x8 b1v = *(const f16x8*)(W1h + (size_t)(16 + l15) * 512 + k);
        acc0 = __builtin_amdgcn_mfma_f32_16x16x32_f16(a, b0, acc0, 0, 0, 0);
        acc1 = __builtin_amdgcn_mfma_f32_16x16x32_f16(a, b1v, acc1, 0, 0, 0);
    }
    #pragma unroll
    for (int j = 0; j < 4; ++j) {
        int srow = wid * 16 + l4 * 4 + j;
        float v0 = acc0[j] + b1[l15];
        float v1 = acc1[j] + b1[16 + l15];
        h1s[srow][l15]      = v0 > 0.f ? v0 : 0.f;
        h1s[srow][16 + l15] = v1 > 0.f ? v1 : 0.f;
    }
    __syncthreads();

    // layers 2+3: 4 lanes per sample, fp32
    const int s_in = lane >> 2, q = lane & 3;
    const int srow = wid * 16 + s_in;
    float h2[8];
    #pragma unroll
    for (int n = 0; n < 8; ++n) {
        int nn = q * 8 + n;
        float sum = b2[nn];
        #pragma unroll
        for (int k = 0; k < 32; ++k) sum += W2[nn * 32 + k] * h1s[srow][k];
        h2[n] = sum > 0.f ? sum : 0.f;
    }
    float p = 0.f;
    #pragma unroll
    for (int n = 0; n < 8; ++n) p += W3[q * 8 + n] * h2[n];
    p += __shfl_xor(p, 1);
    p += __shfl_xor(p, 2);
    if (q == 0) {
        out[s0 + srow] = (p + b3[0]) * stm[s0 + srow];
    }
}

extern "C" void kernel_launch(void* const* d_in, const int* in_sizes, int n_in,
                              void* d_out, int out_size, void* d_ws, size_t ws_size,
                              hipStream_t stream)
{
    const float* wf    = (const float*)d_in[0];
    const float* bfeat = (const float*)d_in[1];
    const int*   wb    = (const int*)d_in[2];
    const int*   bb    = (const int*)d_in[3];
    const float* stm   = (const float*)d_in[4];
    const float* Wft   = (const float*)d_in[5];
    const float* W1    = (const float*)d_in[6];
    const float* b1    = (const float*)d_in[7];
    const float* W2    = (const float*)d_in[8];
    const float* b2    = (const float*)d_in[9];
    const float* W3    = (const float*)d_in[10];
    const float* b3    = (const float*)d_in[11];
    float* out = (float*)d_out;

    char* ws = (char*)d_ws;
    int*   hdr  = (int*)ws;                    // 256 B header (cnt/pofs/cur)
    int*   perm = (int*)(ws + 256);            // 132096 ints -> ends 528640
    f16_t* Whf  = (f16_t*)(ws + 528640);       // 2621440 B  -> ends 3150080
    f16_t* W1h  = (f16_t*)(ws + 3150080);      // 32768 B    -> ends 3182848
    f16_t* cbuf = (f16_t*)(ws + 3182848);      // 67108864 B -> ends ~70.3 MB

    k_init   <<<512, 256, 0, stream>>>(Wft, W1, Whf, W1h, hdr, perm);
    k_hist   <<<512, 256, 0, stream>>>(wb, bb, hdr);
    k_prefix <<<1,   64,  0, stream>>>(hdr);
    k_scatter<<<512, 256, 0, stream>>>(wb, bb, hdr, perm);
    k_gemm   <<<NPERM / PB, 512, 0, stream>>>(wf, bfeat, Whf, hdr, perm, cbuf);
    k_mlp    <<<NB / 64, 256, 0, stream>>>(cbuf, W1h, b1, W2, b2, W3, b3, stm, out);
}